// Round 9
// baseline (116.961 us; speedup 1.0000x reference)
//
#include <hip/hip_runtime.h>
#include <hip/hip_bf16.h>
#include <stdint.h>

#define C_DIM 512
#define T_SEQ 8192
#define N_PROP 16384
#define HID_DIM 1024
#define OUT_DIM 512
#define K2C 1024  // 2*C

typedef __attribute__((ext_vector_type(8))) __bf16 bf16x8;
typedef __attribute__((ext_vector_type(4))) float f32x4;

#define BARRIER() __builtin_amdgcn_s_barrier()
#define SBAR() __builtin_amdgcn_sched_barrier(0)
#define LGKM0() asm volatile("s_waitcnt lgkmcnt(0)" ::: "memory")

// ---------------- cumsum: one wave per channel, float4 chunks, shuffle scan ----------------
__global__ __launch_bounds__(64) void cumsum_kernel(const float* __restrict__ feat,
                                                    float* __restrict__ cs_inc) {
    int c = blockIdx.x;
    const float4* in = (const float4*)(feat + (size_t)c * T_SEQ);
    float4* out = (float4*)(cs_inc + (size_t)c * T_SEQ);
    int lane = threadIdx.x;
    float carry = 0.0f;
    for (int i0 = 0; i0 < T_SEQ / 4; i0 += 64) {
        float4 v = in[i0 + lane];
        float s1 = v.x + v.y;
        float s2 = s1 + v.z;
        float s3 = s2 + v.w;
        float x = s3;
#pragma unroll
        for (int s = 1; s < 64; s <<= 1) {
            float y = __shfl_up(x, s);
            if (lane >= s) x += y;
        }
        float base = carry + (x - s3);
        float4 o;
        o.x = base + v.x; o.y = base + s1; o.z = base + s2; o.w = base + s3;
        out[i0 + lane] = o;
        carry += __shfl(x, 63);
    }
}

// ---------------- transpose cs_inc (C, T) -> cs_t (T+1, C) with leading-zero shift ----------------
__global__ __launch_bounds__(256) void transpose_kernel(const float* __restrict__ cs_inc,
                                                        float* __restrict__ cs_t) {
    __shared__ float tl[32][33];
    int tx = threadIdx.x, ty = threadIdx.y;  // (32, 8)
    int x0 = blockIdx.x * 32;
    int y0 = blockIdx.y * 32;
#pragma unroll
    for (int i = 0; i < 32; i += 8) {
        int t = x0 + tx;
        int ch = y0 + ty + i;
        float v = 0.0f;
        if (t >= 1 && t <= T_SEQ) v = cs_inc[(size_t)ch * T_SEQ + (t - 1)];
        tl[ty + i][tx] = v;
    }
    __syncthreads();
#pragma unroll
    for (int i = 0; i < 32; i += 8) {
        int t = x0 + ty + i;
        int ch = y0 + tx;
        if (t <= T_SEQ) cs_t[(size_t)t * C_DIM + ch] = tl[tx][ty + i];
    }
}

// ---------------- pooling -> e (N, 2C) bf16; 4 proposals/block, float4/thread ----------------
__global__ __launch_bounds__(512) void pool_kernel(const float* __restrict__ cs_t,
                                                   const int* __restrict__ lptr,
                                                   const int* __restrict__ rptr,
                                                   __hip_bfloat16* __restrict__ e) {
    int n = blockIdx.x * 4 + (threadIdx.x >> 7);
    int c4 = (threadIdx.x & 127) * 4;
    int li = lptr[n], ri = rptr[n];
    float w = fmaxf((float)(ri - li), 1.0f);
    int bw = max(1, (int)(0.15f * w));
    int lb_s = max(0, li - bw);
    int lb_e = min(T_SEQ, li + bw);
    int rb_s = max(0, ri - bw);
    int rb_e = min(T_SEQ, ri + bw);
    lb_e = min(max(lb_s + 1, lb_e), T_SEQ);
    rb_e = min(max(rb_s + 1, rb_e), T_SEQ);
    float4 a = *(const float4*)(cs_t + (size_t)lb_e * C_DIM + c4);
    float4 b = *(const float4*)(cs_t + (size_t)lb_s * C_DIM + c4);
    float4 cc = *(const float4*)(cs_t + (size_t)rb_e * C_DIM + c4);
    float4 d = *(const float4*)(cs_t + (size_t)rb_s * C_DIM + c4);
    float rl = 1.0f / (float)(lb_e - lb_s);
    float rr = 1.0f / (float)(rb_e - rb_s);
    __hip_bfloat16 L0 = __float2bfloat16((a.x - b.x) * rl);
    __hip_bfloat16 L1 = __float2bfloat16((a.y - b.y) * rl);
    __hip_bfloat16 L2 = __float2bfloat16((a.z - b.z) * rl);
    __hip_bfloat16 L3 = __float2bfloat16((a.w - b.w) * rl);
    __hip_bfloat16 R0 = __float2bfloat16((cc.x - d.x) * rr);
    __hip_bfloat16 R1 = __float2bfloat16((cc.y - d.y) * rr);
    __hip_bfloat16 R2 = __float2bfloat16((cc.z - d.z) * rr);
    __hip_bfloat16 R3 = __float2bfloat16((cc.w - d.w) * rr);
    ushort4 ul, ur;
    ul.x = *(unsigned short*)&L0; ul.y = *(unsigned short*)&L1;
    ul.z = *(unsigned short*)&L2; ul.w = *(unsigned short*)&L3;
    ur.x = *(unsigned short*)&R0; ur.y = *(unsigned short*)&R1;
    ur.z = *(unsigned short*)&R2; ur.w = *(unsigned short*)&R3;
    *(ushort4*)(e + (size_t)n * K2C + c4) = ul;
    *(ushort4*)(e + (size_t)n * K2C + C_DIM + c4) = ur;
}

// ---------------- fused fp32 -> bf16 convert for W1 and W2 ----------------
__global__ __launch_bounds__(256) void cvt_bf16_kernel(const float* __restrict__ W1,
                                                       const float* __restrict__ W2,
                                                       __hip_bfloat16* __restrict__ W1b,
                                                       __hip_bfloat16* __restrict__ W2b) {
    const int n1 = HID_DIM * K2C;
    int i = (blockIdx.x * 256 + threadIdx.x) * 4;
    const float* src;
    __hip_bfloat16* dst;
    int j;
    if (i < n1) { src = W1; dst = W1b; j = i; }
    else        { src = W2; dst = W2b; j = i - n1; }
    float4 v = *(const float4*)(src + j);
    __hip_bfloat16 h0 = __float2bfloat16(v.x);
    __hip_bfloat16 h1 = __float2bfloat16(v.y);
    __hip_bfloat16 h2 = __float2bfloat16(v.z);
    __hip_bfloat16 h3 = __float2bfloat16(v.w);
    ushort4 u;
    u.x = *(unsigned short*)&h0; u.y = *(unsigned short*)&h1;
    u.z = *(unsigned short*)&h2; u.w = *(unsigned short*)&h3;
    *(ushort4*)(dst + j) = u;
}

// ---------------- fine-grained 8-phase GEMM (m201-style, T2+T3+T4+T5) ----------------
// C[m][n] = sum_k A[m][k]*B[n][k] (+bias, optional relu->bf16). BK=64, 512 thr = 8 waves.
// Iter = 2 K-tiles (u0=2i slot0, u1=2i+1 slot1), 8 phases, 16(8) MFMA + <=12 ds_read +
// <=2 global_load_lds per phase. Phase = {reads?; stage; BAR; sched_barrier;
// setprio(1); MFMA-cluster; setprio(0); [vmcnt]; BAR}.
// Reads: P0/P1 issue ALL slot0 frags (kk0,kk1); P4/P5 for slot1. lgkmcnt(0) at end of
// P1/P5 ensures slot reads drained before opposite staging (WAR-safe).
// Stage slices/tile (LPT loads): u1 tail @P0,P1; u0+2 @P2..P5; u1+2 head @P6,P7.
// Publish (wait-then-barrier): vmcnt(4) after P3-MFMA -> tile u1 landed (P2,P3's 4
// younger); vmcnt(4) after P7-MFMA -> tile u0+2 landed (P6,P7's 4 younger).
// Tail iter: counts drop to 0. Prologue: tile0 full + tile1 first 4; vmcnt(4); BAR.
template <int BM, int BN, int WM, int WN, int K, int RELU_BF16>
__global__ __launch_bounds__(512, 2) void gemm8f_kernel(const __hip_bfloat16* __restrict__ A,
                                                        const __hip_bfloat16* __restrict__ B,
                                                        const float* __restrict__ bias,
                                                        void* __restrict__ Cout,
                                                        int Nc, int NBlk) {
    constexpr int BK = 64;
    constexpr int NT = K / BK;
    constexpr int NI = NT / 2;
    constexpr int WMT = BM / WM, WNT = BN / WN;
    constexpr int MR = WMT / 16, NR = WNT / 16;
    constexpr int MH = MR / 2;
    constexpr int LA = BM / 64, LB = BN / 64;
    constexpr int LPT = LA + LB;          // 8 (GEMM1) / 6 (GEMM2)
    constexpr int TC = LPT - 4;           // tail loads split over two phases
    constexpr int TCa = TC - TC / 2, TCb = TC / 2;

    __shared__ __align__(16) __hip_bfloat16 As[2][BM * BK];
    __shared__ __align__(16) __hip_bfloat16 Bs[2][BN * BK];

    const int tid = threadIdx.x;
    const int lane = tid & 63;
    const int wid = tid >> 6;
    const int wm = wid / WN;
    const int wn = wid % WN;

    const int nwg = gridDim.x;  // 256 (multiple of 8)
    const int wg = (blockIdx.x & 7) * (nwg >> 3) + (blockIdx.x >> 3);
    const long m0 = (long)(wg / NBlk) * BM;
    const long n0 = (long)(wg % NBlk) * BN;

    const int srow = tid >> 3;                  // staging row in 64-row round
    const int schunk = (tid & 7) ^ (srow & 7);  // pre-swizzled 16B source granule (T2)
    const int fr = lane & 15;
    const int g8 = (lane >> 4) * 8;

    f32x4 acc[MR][NR] = {};

    auto stage_one = [&](int s, long k0, int j) {
        if (j < LA)
            __builtin_amdgcn_global_load_lds(
                (const __attribute__((address_space(1))) void*)(A + (m0 + j * 64 + srow) * K + k0 + schunk * 8),
                (__attribute__((address_space(3))) void*)(&As[s][j * 4096 + tid * 8]), 16, 0, 0);
        else
            __builtin_amdgcn_global_load_lds(
                (const __attribute__((address_space(1))) void*)(B + (n0 + (j - LA) * 64 + srow) * K + k0 + schunk * 8),
                (__attribute__((address_space(3))) void*)(&Bs[s][(j - LA) * 4096 + tid * 8]), 16, 0, 0);
    };
    auto ldA = [&](int s, int row, int kbase) -> bf16x8 {
        return *(const bf16x8*)(&As[s][row * BK + ((kbase + g8) ^ ((row & 7) * 8))]);
    };
    auto ldB = [&](int s, int row, int kbase) -> bf16x8 {
        return *(const bf16x8*)(&Bs[s][row * BK + ((kbase + g8) ^ ((row & 7) * 8))]);
    };

    bf16x8 af0[MR], af1[MR], bv0[NR], bv1[NR];

    auto rd = [&](int s, int kb, bf16x8* af, bf16x8* bv) {
#pragma unroll
        for (int m = 0; m < MR; ++m) af[m] = ldA(s, wm * WMT + m * 16 + fr, kb);
#pragma unroll
        for (int n = 0; n < NR; ++n) bv[n] = ldB(s, wn * WNT + n * 16 + fr, kb);
    };
    auto mf = [&](const bf16x8* af, const bf16x8* bv, int mlo) {
        __builtin_amdgcn_s_setprio(1);
#pragma unroll
        for (int m = 0; m < MH; ++m)
#pragma unroll
            for (int n = 0; n < NR; ++n)
                acc[mlo + m][n] =
                    __builtin_amdgcn_mfma_f32_16x16x32_bf16(af[mlo + m], bv[n], acc[mlo + m][n], 0, 0, 0);
        __builtin_amdgcn_s_setprio(0);
    };

    // ---- prologue: tile0 full + tile1 first 4; publish tile0 ----
#pragma unroll
    for (int j = 0; j < LPT; ++j) stage_one(0, 0, j);
#pragma unroll
    for (int j = 0; j < 4; ++j) stage_one(1, BK, j);
    asm volatile("s_waitcnt vmcnt(4)" ::: "memory");
    BARRIER();

#pragma unroll 1
    for (int i = 0; i < NI; ++i) {
        const long u1 = 2 * i + 1;
        const bool sE = (2 * i + 2 < NT);   // stage tile u0+2?
        const bool sO = (2 * i + 3 < NT);   // stage tile u1+2?
        const long kE = (2 * i + 2) * BK, kO = (2 * i + 3) * BK, kU1 = u1 * BK;

        // ---- P0 ----
        rd(0, 0, af0, bv0);
#pragma unroll
        for (int j = 4; j < 4 + TCa; ++j) stage_one(1, kU1, j);
        BARRIER(); SBAR();
        mf(af0, bv0, 0);
        BARRIER();
        // ---- P1 ----
        rd(0, 32, af1, bv1);
#pragma unroll
        for (int j = 4 + TCa; j < LPT; ++j) stage_one(1, kU1, j);
        BARRIER(); SBAR();
        mf(af0, bv0, MH);
        LGKM0();       // slot0 reads drained before P2 stages into slot0
        BARRIER();
        // ---- P2 ----
        if (sE) { stage_one(0, kE, 0); stage_one(0, kE, 1); }
        BARRIER(); SBAR();
        mf(af1, bv1, 0);
        BARRIER();
        // ---- P3 ----
        if (sE) { stage_one(0, kE, 2); stage_one(0, kE, 3); }
        BARRIER(); SBAR();
        mf(af1, bv1, MH);
        if (sE) asm volatile("s_waitcnt vmcnt(4)" ::: "memory");  // publish tile u1
        else    asm volatile("s_waitcnt vmcnt(0)" ::: "memory");
        BARRIER();
        // ---- P4 ----
        rd(1, 0, af0, bv0);
        if (sE) {
#pragma unroll
            for (int j = 4; j < 4 + TCa; ++j) stage_one(0, kE, j);
        }
        BARRIER(); SBAR();
        mf(af0, bv0, 0);
        BARRIER();
        // ---- P5 ----
        rd(1, 32, af1, bv1);
        if (sE) {
#pragma unroll
            for (int j = 4 + TCa; j < LPT; ++j) stage_one(0, kE, j);
        }
        BARRIER(); SBAR();
        mf(af0, bv0, MH);
        LGKM0();       // slot1 reads drained before P6 stages into slot1
        BARRIER();
        // ---- P6 ----
        if (sO) { stage_one(1, kO, 0); stage_one(1, kO, 1); }
        BARRIER(); SBAR();
        mf(af1, bv1, 0);
        BARRIER();
        // ---- P7 ----
        if (sO) { stage_one(1, kO, 2); stage_one(1, kO, 3); }
        BARRIER(); SBAR();
        mf(af1, bv1, MH);
        if (sO) asm volatile("s_waitcnt vmcnt(4)" ::: "memory");  // publish tile u0+2
        else if (sE) asm volatile("s_waitcnt vmcnt(0)" ::: "memory");
        BARRIER();
    }

    const int rq = (lane >> 4) * 4;
#pragma unroll
    for (int m = 0; m < MR; ++m)
#pragma unroll
        for (int n = 0; n < NR; ++n) {
            long col = n0 + wn * WNT + n * 16 + fr;
            float bb = bias[col];
#pragma unroll
            for (int q = 0; q < 4; ++q) {
                long row = m0 + wm * WMT + m * 16 + rq + q;
                float v = acc[m][n][q] + bb;
                if (RELU_BF16) {
                    v = fmaxf(v, 0.0f);
                    ((__hip_bfloat16*)Cout)[row * Nc + col] = __float2bfloat16(v);
                } else {
                    ((float*)Cout)[row * Nc + col] = v;
                }
            }
        }
}

extern "C" void kernel_launch(void* const* d_in, const int* in_sizes, int n_in,
                              void* d_out, int out_size, void* d_ws, size_t ws_size,
                              hipStream_t stream) {
    const float* feat = (const float*)d_in[0];
    const int* l = (const int*)d_in[1];
    const int* r = (const int*)d_in[2];
    const float* W1 = (const float*)d_in[4];
    const float* b1 = (const float*)d_in[5];
    const float* W2 = (const float*)d_in[6];
    const float* b2 = (const float*)d_in[7];

    char* ws = (char*)d_ws;
    float* cs_t = (float*)ws;                                    // 8193*512*4
    __hip_bfloat16* e = (__hip_bfloat16*)(ws + 16779264);        // 16384*1024*2
    __hip_bfloat16* h = (__hip_bfloat16*)(ws + 50333696);        // 16384*1024*2 (aliases cs_inc)
    float* cs_inc = (float*)(ws + 50333696);                     // 512*8192*4, dead before h
    __hip_bfloat16* W1b = (__hip_bfloat16*)(ws + 83888128);      // 1024*1024*2
    __hip_bfloat16* W2b = (__hip_bfloat16*)(ws + 85985280);      // 512*1024*2

    const int ncvt = (HID_DIM * K2C + OUT_DIM * HID_DIM) / 4 / 256;
    cvt_bf16_kernel<<<dim3(ncvt), 256, 0, stream>>>(W1, W2, W1b, W2b);
    cumsum_kernel<<<dim3(C_DIM), 64, 0, stream>>>(feat, cs_inc);
    transpose_kernel<<<dim3((T_SEQ + 32) / 32, C_DIM / 32), dim3(32, 8), 0, stream>>>(cs_inc, cs_t);
    pool_kernel<<<dim3(N_PROP / 4), 512, 0, stream>>>(cs_t, l, r, e);

    // GEMM1: h = relu(e @ W1^T + b1). 256x256, waves 2x4 (wave 128x64), 256 blocks.
    gemm8f_kernel<256, 256, 2, 4, K2C, 1>
        <<<dim3((N_PROP / 256) * (HID_DIM / 256)), 512, 0, stream>>>(e, W1b, b1, h, HID_DIM, HID_DIM / 256);
    // GEMM2: out = h @ W2^T + b2. 256x128, waves 4x2 (wave 64x64), 256 blocks.
    gemm8f_kernel<256, 128, 4, 2, HID_DIM, 0>
        <<<dim3((N_PROP / 256) * (OUT_DIM / 128)), 512, 0, stream>>>(h, W2b, b2, d_out, OUT_DIM, OUT_DIM / 128);
}